// Round 4
// baseline (624.466 us; speedup 1.0000x reference)
//
#include <hip/hip_runtime.h>

// GCN 2-layer: N=100000, E=3200000, IN=8, HID=64, OUT=1.
// Round 4: atomic-free CSR build (partitioned counting sort, all counters in
// LDS). R3 was bound by global atomic throughput (k_fill 250us = 3.2M
// returning atomics @ ~13G/s, 198MB write-through; k_hist ~150us similar).
//
// Partition: edges into C=32 chunks of 100K; cols into ranges.
//   hist: 4 ranges x 32768 bins (u16 pairs packed in u32, 64KB LDS)
//   fill: 7 ranges x 16384 bins (u32 absolute cursors, 64KB LDS)
// partial[c][n] (stride NB=131072) carries per-(chunk,node) counts ->
// exclusive prefix across chunks -> LDS bump gives unique CSR slots.

#define N_  100000
#define E_  3200000
#define C_  32
#define CS  100000        // E_/C_
#define NB  131072        // per-chunk stride in partial (covers 4*32768)
#define NBLK 391          // ceil(N_/256)

// ---- hist: per-(range4, chunk) 32768-bin LDS histogram, packed u16 pairs
__global__ void k_hist2(const int* __restrict__ col, int* __restrict__ partial) {
    __shared__ unsigned int bins[16384];
    int r = blockIdx.x >> 5;          // /C_
    int c = blockIdx.x & 31;
    int t = threadIdx.x;
    for (int i = t; i < 16384; i += 256) bins[i] = 0u;
    __syncthreads();
    int base = r << 15;               // r*32768
    const int* cp = col + c * CS;
    for (int e = t; e < CS; e += 256) {
        int v = cp[e] - base;
        if ((unsigned)v < 32768u)
            atomicAdd(&bins[v >> 1], (v & 1) ? 65536u : 1u);
    }
    __syncthreads();
    int2* out = (int2*)(partial + (size_t)c * NB + base);
    for (int i = t; i < 16384; i += 256) {
        unsigned int wd = bins[i];
        out[i] = make_int2((int)(wd & 0xFFFFu), (int)(wd >> 16));
    }
}

// ---- per-node exclusive prefix across chunks; total -> cnt[n]
__global__ void k_colscan(int* __restrict__ partial, int* __restrict__ cnt) {
    int n = blockIdx.x * 256 + threadIdx.x;   // bin id in [0, NB)
    int run = 0;
    #pragma unroll 4
    for (int c = 0; c < C_; c++) {
        size_t idx = (size_t)c * NB + n;
        int v = partial[idx];
        partial[idx] = run;
        run += v;
    }
    if (n < N_) cnt[n] = run;
}

// ---- exclusive scan over cnt -> ptr (block scan + block-sum scan + add)
__global__ void k_scan_blk(const int* __restrict__ cnt, int* __restrict__ ptr,
                           int* __restrict__ pblk, int n) {
    __shared__ int sm[256];
    int t = threadIdx.x;
    int i = blockIdx.x * 256 + t;
    int v = (i < n) ? cnt[i] : 0;
    sm[t] = v;
    __syncthreads();
    for (int off = 1; off < 256; off <<= 1) {
        int add = (t >= off) ? sm[t - off] : 0;
        __syncthreads();
        sm[t] += add;
        __syncthreads();
    }
    if (i < n) ptr[i] = sm[t] - v;
    if (t == 255) pblk[blockIdx.x] = sm[t];
}

__global__ void k_scan_part(int* __restrict__ pblk, int nblk) {
    __shared__ int sm[512];
    int t = threadIdx.x;
    int v = (t < nblk) ? pblk[t] : 0;
    sm[t] = v;
    __syncthreads();
    for (int off = 1; off < 512; off <<= 1) {
        int add = (t >= off) ? sm[t - off] : 0;
        __syncthreads();
        sm[t] += add;
        __syncthreads();
    }
    if (t < nblk) pblk[t] = sm[t] - v;
}

__global__ void k_scan_add(int* __restrict__ ptr, const int* __restrict__ pblk, int n) {
    int i = blockIdx.x * 256 + threadIdx.x;
    if (i < n) ptr[i] += pblk[blockIdx.x];
}

// ---- fill: per-(range7, chunk); LDS cursors = ptr[n] + chunk prefix
__global__ void k_fill2(const int* __restrict__ row, const int* __restrict__ col,
                        const float* __restrict__ w,
                        const int* __restrict__ ptr, const int* __restrict__ partial,
                        int2* __restrict__ rec) {
    __shared__ int curs[16384];
    int r = blockIdx.x >> 5;          // /C_
    int c = blockIdx.x & 31;
    int t = threadIdx.x;
    int base = r * 16384;
    const int* pp = partial + (size_t)c * NB + base;
    for (int i = t; i < 16384; i += 256) {
        int n = base + i;
        curs[i] = (n < N_) ? (ptr[n] + pp[i]) : 0;
    }
    __syncthreads();
    const int* cp = col + c * CS;
    const int* rp = row + c * CS;
    const float* wp = w + c * CS;
    for (int e = t; e < CS; e += 256) {
        int v = cp[e] - base;
        if ((unsigned)v < 16384u) {
            int pos = atomicAdd(&curs[v], 1);       // LDS atomic only
            rec[pos] = make_int2(rp[e], __float_as_int(wp[e]));
        }
    }
}

// ---- weighted degree via gather; dinv = rsqrt(deg + 1)
__global__ void k_deg(const int* __restrict__ ptr, const int* __restrict__ cnt,
                      const int2* __restrict__ rec, float* __restrict__ dinv, int n) {
    int i = blockIdx.x * blockDim.x + threadIdx.x;
    if (i >= n) return;
    int st = ptr[i], en = st + cnt[i];
    float d = 0.0f;
    #pragma unroll 4
    for (int e = st; e < en; e++) d += __int_as_float(rec[e].y);
    dinv[i] = rsqrtf(d + 1.0f);
}

// ---- fused: agg 8-wide (+self-loop), h=a@W1+b1, relu, s=h@W2; cache norm
__global__ void k_aggnode(const int* __restrict__ ptr, const int* __restrict__ cnt,
                          int2* __restrict__ rec,
                          const float* __restrict__ dinv,
                          const float* __restrict__ x,
                          const float* __restrict__ W1,
                          const float* __restrict__ b1,
                          const float* __restrict__ W2,
                          float* __restrict__ s, int n) {
    __shared__ float sW1[8 * 64];
    __shared__ float sb1[64];
    __shared__ float sW2[64];
    int t = threadIdx.x;
    for (int k = t; k < 8 * 64; k += blockDim.x) sW1[k] = W1[k];
    if (t < 64) { sb1[t] = b1[t]; sW2[t] = W2[t]; }
    __syncthreads();
    int i = blockIdx.x * blockDim.x + t;
    if (i >= n) return;
    float di = dinv[i];
    float sl = di * di;
    const float4* xi = (const float4*)(x + (size_t)i * 8);
    float4 x0 = xi[0], x1 = xi[1];
    float a[8];
    a[0] = sl * x0.x; a[1] = sl * x0.y; a[2] = sl * x0.z; a[3] = sl * x0.w;
    a[4] = sl * x1.x; a[5] = sl * x1.y; a[6] = sl * x1.z; a[7] = sl * x1.w;
    int st = ptr[i], en = st + cnt[i];
    #pragma unroll 2
    for (int e = st; e < en; e++) {
        int2 rc = rec[e];
        int r = rc.x;
        float nrm = dinv[r] * __int_as_float(rc.y) * di;
        rec[e].y = __float_as_int(nrm);      // cache norm for layer 2
        const float4* xr = (const float4*)(x + (size_t)r * 8);
        float4 v0 = xr[0], v1 = xr[1];
        a[0] = fmaf(nrm, v0.x, a[0]); a[1] = fmaf(nrm, v0.y, a[1]);
        a[2] = fmaf(nrm, v0.z, a[2]); a[3] = fmaf(nrm, v0.w, a[3]);
        a[4] = fmaf(nrm, v1.x, a[4]); a[5] = fmaf(nrm, v1.y, a[5]);
        a[6] = fmaf(nrm, v1.z, a[6]); a[7] = fmaf(nrm, v1.w, a[7]);
    }
    float acc = 0.0f;
    #pragma unroll
    for (int j = 0; j < 64; j++) {
        float h = sb1[j];
        #pragma unroll
        for (int k = 0; k < 8; k++) h = fmaf(a[k], sW1[k * 64 + j], h);
        acc = fmaf(fmaxf(h, 0.0f), sW2[j], acc);
    }
    s[i] = acc;
}

// ---- layer-2 propagation via gather
__global__ void k_out2(const int* __restrict__ ptr, const int* __restrict__ cnt,
                       const int2* __restrict__ rec,
                       const float* __restrict__ dinv,
                       const float* __restrict__ s,
                       const float* __restrict__ b2,
                       float* __restrict__ out, int n) {
    int i = blockIdx.x * blockDim.x + threadIdx.x;
    if (i >= n) return;
    float di = dinv[i];
    float acc = b2[0] + di * di * s[i];
    int st = ptr[i], en = st + cnt[i];
    #pragma unroll 4
    for (int e = st; e < en; e++) {
        int2 rc = rec[e];
        acc = fmaf(__int_as_float(rc.y), s[rc.x], acc);
    }
    out[i] = acc;
}

extern "C" void kernel_launch(void* const* d_in, const int* in_sizes, int n_in,
                              void* d_out, int out_size, void* d_ws, size_t ws_size,
                              hipStream_t stream) {
    const float* x  = (const float*)d_in[0];
    const int*   ei = (const int*)d_in[1];    // [2, E] int32
    const float* w  = (const float*)d_in[2];
    const float* W1 = (const float*)d_in[3];
    const float* b1 = (const float*)d_in[4];
    const float* W2 = (const float*)d_in[5];
    const float* b2 = (const float*)d_in[6];
    float* out = (float*)d_out;

    const int* row = ei;
    const int* col = ei + E_;

    // ws layout (ints): cnt[N] | ptr[N] | partial[C_*NB] | pblk[512] |
    //                   dinv[N] | s[N] | rec[2*E]   (~44 MB)
    int*   wsI     = (int*)d_ws;
    int*   cnt     = wsI;
    int*   ptr     = wsI + N_;
    int*   partial = wsI + 2 * N_;
    int*   pblk    = partial + (size_t)C_ * NB;
    float* dinv    = (float*)(pblk + 512);
    float* s       = dinv + N_;
    int2*  rec     = (int2*)(s + N_);

    k_hist2    <<<4 * C_, 256, 0, stream>>>(col, partial);
    k_colscan  <<<NB / 256, 256, 0, stream>>>(partial, cnt);
    k_scan_blk <<<NBLK, 256, 0, stream>>>(cnt, ptr, pblk, N_);
    k_scan_part<<<1, 512, 0, stream>>>(pblk, NBLK);
    k_scan_add <<<NBLK, 256, 0, stream>>>(ptr, pblk, N_);
    k_fill2    <<<7 * C_, 256, 0, stream>>>(row, col, w, ptr, partial, rec);
    k_deg      <<<NBLK, 256, 0, stream>>>(ptr, cnt, rec, dinv, N_);
    k_aggnode  <<<NBLK, 256, 0, stream>>>(ptr, cnt, rec, dinv, x, W1, b1, W2, s, N_);
    k_out2     <<<NBLK, 256, 0, stream>>>(ptr, cnt, rec, dinv, s, b2, out, N_);
}

// Round 5
// 393.582 us; speedup vs baseline: 1.5866x; 1.5866x over previous
//
#include <hip/hip_runtime.h>

// GCN 2-layer: N=100000, E=3200000, IN=8, HID=64, OUT=1.
// Round 5: same atomic-free partitioned counting sort as R4, but sized for
// occupancy. R4's fill was latency-bound (2% VALU, 9.7% occupancy: 64KB LDS
// => 2 blocks/CU, 224 blocks total). Now 16KB LDS bins, 64 edge chunks:
//   hist: 13 ranges x 64 chunks = 832 blocks  (8192 nodes/range, u16-packed)
//   fill: 25 ranges x 64 chunks = 1600 blocks (4096 nodes/range, int cursors)
// Per-(chunk,node) partial counts in u16 (chunk size 50000 < 65536: safe).
// Redundant col re-reads per range are LLC-resident (38MB inputs vs 256MB L3).

#define N_   100000
#define E_   3200000
#define C_   64          // edge chunks
#define CS   50000       // E_/C_
#define HB_  8192        // nodes per hist range
#define RH_  13          // ceil(N_/HB_)
#define FB_  4096        // nodes per fill range
#define RF_  25          // ceil(N_/FB_)
#define NB16 106496      // u16 stride per chunk (RH_*HB_ = 13*8192)
#define NBLK 391         // ceil(N_/256)

// ---- hist: per-(range,chunk) LDS histogram, 2 nodes packed per u32
__global__ void k_hist3(const int* __restrict__ col,
                        unsigned short* __restrict__ part16) {
    __shared__ unsigned int bins[HB_ / 2];
    int r = blockIdx.x >> 6;          // / C_
    int c = blockIdx.x & 63;
    int t = threadIdx.x;
    for (int i = t; i < HB_ / 2; i += 256) bins[i] = 0u;
    __syncthreads();
    int base = r * HB_;
    const int* cp = col + c * CS;
    for (int e = t; e < CS; e += 256) {
        int v = cp[e] - base;
        if ((unsigned)v < (unsigned)HB_)
            atomicAdd(&bins[v >> 1], (v & 1) ? 65536u : 1u);
    }
    __syncthreads();
    unsigned int* outp = (unsigned int*)(part16 + (size_t)c * NB16 + base);
    for (int i = t; i < HB_ / 2; i += 256) outp[i] = bins[i];
}

// ---- per-node exclusive prefix across chunks (in u16); totals -> cnt
__global__ void k_colscan(unsigned short* __restrict__ part16,
                          int* __restrict__ cnt) {
    int n = blockIdx.x * 256 + threadIdx.x;      // [0, NB16)
    int run = 0;
    #pragma unroll 8
    for (int c = 0; c < C_; c++) {
        size_t idx = (size_t)c * NB16 + n;
        int v = part16[idx];
        part16[idx] = (unsigned short)run;       // max degree ~80 here: fits
        run += v;
    }
    if (n < N_) cnt[n] = run;
}

// ---- exclusive scan over cnt -> ptr
__global__ void k_scan_blk(const int* __restrict__ cnt, int* __restrict__ ptr,
                           int* __restrict__ pblk, int n) {
    __shared__ int sm[256];
    int t = threadIdx.x;
    int i = blockIdx.x * 256 + t;
    int v = (i < n) ? cnt[i] : 0;
    sm[t] = v;
    __syncthreads();
    for (int off = 1; off < 256; off <<= 1) {
        int add = (t >= off) ? sm[t - off] : 0;
        __syncthreads();
        sm[t] += add;
        __syncthreads();
    }
    if (i < n) ptr[i] = sm[t] - v;
    if (t == 255) pblk[blockIdx.x] = sm[t];
}

__global__ void k_scan_part(int* __restrict__ pblk, int nblk) {
    __shared__ int sm[512];
    int t = threadIdx.x;
    int v = (t < nblk) ? pblk[t] : 0;
    sm[t] = v;
    __syncthreads();
    for (int off = 1; off < 512; off <<= 1) {
        int add = (t >= off) ? sm[t - off] : 0;
        __syncthreads();
        sm[t] += add;
        __syncthreads();
    }
    if (t < nblk) pblk[t] = sm[t] - v;
}

__global__ void k_scan_add(int* __restrict__ ptr, const int* __restrict__ pblk, int n) {
    int i = blockIdx.x * 256 + threadIdx.x;
    if (i < n) ptr[i] += pblk[blockIdx.x];
}

// ---- fill: per-(range,chunk); LDS cursors = ptr[n] + chunk prefix
__global__ void k_fill3(const int* __restrict__ row, const int* __restrict__ col,
                        const float* __restrict__ w,
                        const int* __restrict__ ptr,
                        const unsigned short* __restrict__ part16,
                        int2* __restrict__ rec) {
    __shared__ int curs[FB_];
    int r = blockIdx.x >> 6;          // / C_
    int c = blockIdx.x & 63;
    int t = threadIdx.x;
    int base = r * FB_;
    const unsigned short* pp = part16 + (size_t)c * NB16 + base;
    for (int i = t; i < FB_; i += 256) {
        int n = base + i;
        curs[i] = (n < N_) ? (ptr[n] + (int)pp[i]) : 0;
    }
    __syncthreads();
    const int* cp = col + c * CS;
    const int* rp = row + c * CS;
    const float* wp = w + c * CS;
    for (int e = t; e < CS; e += 256) {
        int v = cp[e] - base;
        if ((unsigned)v < (unsigned)FB_) {
            int pos = atomicAdd(&curs[v], 1);       // LDS atomic only
            rec[pos] = make_int2(rp[e], __float_as_int(wp[e]));
        }
    }
}

// ---- weighted degree via gather; dinv = rsqrt(deg + 1)
__global__ void k_deg(const int* __restrict__ ptr, const int* __restrict__ cnt,
                      const int2* __restrict__ rec, float* __restrict__ dinv, int n) {
    int i = blockIdx.x * blockDim.x + threadIdx.x;
    if (i >= n) return;
    int st = ptr[i], en = st + cnt[i];
    float d = 0.0f;
    #pragma unroll 4
    for (int e = st; e < en; e++) d += __int_as_float(rec[e].y);
    dinv[i] = rsqrtf(d + 1.0f);
}

// ---- fused: agg 8-wide (+self-loop), h=a@W1+b1, relu, s=h@W2
__global__ void k_aggnode(const int* __restrict__ ptr, const int* __restrict__ cnt,
                          const int2* __restrict__ rec,
                          const float* __restrict__ dinv,
                          const float* __restrict__ x,
                          const float* __restrict__ W1,
                          const float* __restrict__ b1,
                          const float* __restrict__ W2,
                          float* __restrict__ s, int n) {
    __shared__ float sW1[8 * 64];
    __shared__ float sb1[64];
    __shared__ float sW2[64];
    int t = threadIdx.x;
    for (int k = t; k < 8 * 64; k += blockDim.x) sW1[k] = W1[k];
    if (t < 64) { sb1[t] = b1[t]; sW2[t] = W2[t]; }
    __syncthreads();
    int i = blockIdx.x * blockDim.x + t;
    if (i >= n) return;
    float di = dinv[i];
    float sl = di * di;
    const float4* xi = (const float4*)(x + (size_t)i * 8);
    float4 x0 = xi[0], x1 = xi[1];
    float a[8];
    a[0] = sl * x0.x; a[1] = sl * x0.y; a[2] = sl * x0.z; a[3] = sl * x0.w;
    a[4] = sl * x1.x; a[5] = sl * x1.y; a[6] = sl * x1.z; a[7] = sl * x1.w;
    int st = ptr[i], en = st + cnt[i];
    #pragma unroll 2
    for (int e = st; e < en; e++) {
        int2 rc = rec[e];
        int r = rc.x;
        float nrm = dinv[r] * __int_as_float(rc.y) * di;
        const float4* xr = (const float4*)(x + (size_t)r * 8);
        float4 v0 = xr[0], v1 = xr[1];
        a[0] = fmaf(nrm, v0.x, a[0]); a[1] = fmaf(nrm, v0.y, a[1]);
        a[2] = fmaf(nrm, v0.z, a[2]); a[3] = fmaf(nrm, v0.w, a[3]);
        a[4] = fmaf(nrm, v1.x, a[4]); a[5] = fmaf(nrm, v1.y, a[5]);
        a[6] = fmaf(nrm, v1.z, a[6]); a[7] = fmaf(nrm, v1.w, a[7]);
    }
    float acc = 0.0f;
    #pragma unroll
    for (int j = 0; j < 64; j++) {
        float h = sb1[j];
        #pragma unroll
        for (int k = 0; k < 8; k++) h = fmaf(a[k], sW1[k * 64 + j], h);
        acc = fmaf(fmaxf(h, 0.0f), sW2[j], acc);
    }
    s[i] = acc;
}

// ---- layer-2 propagation via gather; norm recomputed (dinv is L2-resident)
__global__ void k_out2(const int* __restrict__ ptr, const int* __restrict__ cnt,
                       const int2* __restrict__ rec,
                       const float* __restrict__ dinv,
                       const float* __restrict__ s,
                       const float* __restrict__ b2,
                       float* __restrict__ out, int n) {
    int i = blockIdx.x * blockDim.x + threadIdx.x;
    if (i >= n) return;
    float di = dinv[i];
    float acc = b2[0] + di * di * s[i];
    int st = ptr[i], en = st + cnt[i];
    #pragma unroll 4
    for (int e = st; e < en; e++) {
        int2 rc = rec[e];
        float nrm = dinv[rc.x] * __int_as_float(rc.y) * di;
        acc = fmaf(nrm, s[rc.x], acc);
    }
    out[i] = acc;
}

extern "C" void kernel_launch(void* const* d_in, const int* in_sizes, int n_in,
                              void* d_out, int out_size, void* d_ws, size_t ws_size,
                              hipStream_t stream) {
    const float* x  = (const float*)d_in[0];
    const int*   ei = (const int*)d_in[1];    // [2, E] int32
    const float* w  = (const float*)d_in[2];
    const float* W1 = (const float*)d_in[3];
    const float* b1 = (const float*)d_in[4];
    const float* W2 = (const float*)d_in[5];
    const float* b2 = (const float*)d_in[6];
    float* out = (float*)d_out;

    const int* row = ei;
    const int* col = ei + E_;

    // ws (ints): cnt[N] | ptr[N] | pblk[512] | dinv[N] | s[N] |
    //            part16 (C_*NB16 u16 = 13.6MB) | rec[E] int2 (25.6MB)  ~41MB
    int*   wsI  = (int*)d_ws;
    int*   cnt  = wsI;
    int*   ptr  = wsI + N_;
    int*   pblk = wsI + 2 * N_;
    float* dinv = (float*)(wsI + 2 * N_ + 512);
    float* s    = dinv + N_;
    unsigned short* part16 = (unsigned short*)(s + N_);
    int2*  rec  = (int2*)(part16 + (size_t)C_ * NB16);

    k_hist3    <<<RH_ * C_, 256, 0, stream>>>(col, part16);
    k_colscan  <<<NB16 / 256, 256, 0, stream>>>(part16, cnt);
    k_scan_blk <<<NBLK, 256, 0, stream>>>(cnt, ptr, pblk, N_);
    k_scan_part<<<1, 512, 0, stream>>>(pblk, NBLK);
    k_scan_add <<<NBLK, 256, 0, stream>>>(ptr, pblk, N_);
    k_fill3    <<<RF_ * C_, 256, 0, stream>>>(row, col, w, ptr, part16, rec);
    k_deg      <<<NBLK, 256, 0, stream>>>(ptr, cnt, rec, dinv, N_);
    k_aggnode  <<<NBLK, 256, 0, stream>>>(ptr, cnt, rec, dinv, x, W1, b1, W2, s, N_);
    k_out2     <<<NBLK, 256, 0, stream>>>(ptr, cnt, rec, dinv, s, b2, out, N_);
}

// Round 6
// 368.413 us; speedup vs baseline: 1.6950x; 1.0683x over previous
//
#include <hip/hip_runtime.h>

// GCN 2-layer: N=100000, E=3200000, IN=8, HID=64, OUT=1.
// Round 6: R5 structure (atomic-free partitioned counting sort) + 4-wide
// ILP batching in hist/fill. R5's fill was latency-bound (VALUBusy 11%,
// HBM 9%): one col-load -> LDS-atomic -> scatter-store chain per thread per
// iteration. Batching 4 independent col loads per iteration quadruples MLP.

#define N_   100000
#define E_   3200000
#define C_   64          // edge chunks
#define CS   50000       // E_/C_
#define HB_  8192        // nodes per hist range
#define RH_  13          // ceil(N_/HB_)
#define FB_  4096        // nodes per fill range
#define RF_  25          // ceil(N_/FB_)
#define NB16 106496      // u16 stride per chunk (RH_*HB_)
#define NBLK 391         // ceil(N_/256)
#define ITER 48          // CS/1024 main-loop iterations (4 edges/thread each)

// ---- hist: per-(range,chunk) LDS histogram, 2 nodes packed per u32
__global__ void k_hist3(const int* __restrict__ col,
                        unsigned short* __restrict__ part16) {
    __shared__ unsigned int bins[HB_ / 2];
    int r = blockIdx.x >> 6;          // / C_
    int c = blockIdx.x & 63;
    int t = threadIdx.x;
    for (int i = t; i < HB_ / 2; i += 256) bins[i] = 0u;
    __syncthreads();
    int base = r * HB_;
    const int* cp = col + c * CS;
    int e = t;
    for (int it = 0; it < ITER; it++, e += 1024) {
        int v0 = cp[e]       - base;
        int v1 = cp[e + 256] - base;
        int v2 = cp[e + 512] - base;
        int v3 = cp[e + 768] - base;
        if ((unsigned)v0 < (unsigned)HB_) atomicAdd(&bins[v0 >> 1], (v0 & 1) ? 65536u : 1u);
        if ((unsigned)v1 < (unsigned)HB_) atomicAdd(&bins[v1 >> 1], (v1 & 1) ? 65536u : 1u);
        if ((unsigned)v2 < (unsigned)HB_) atomicAdd(&bins[v2 >> 1], (v2 & 1) ? 65536u : 1u);
        if ((unsigned)v3 < (unsigned)HB_) atomicAdd(&bins[v3 >> 1], (v3 & 1) ? 65536u : 1u);
    }
    for (; e < CS; e += 256) {
        int v = cp[e] - base;
        if ((unsigned)v < (unsigned)HB_) atomicAdd(&bins[v >> 1], (v & 1) ? 65536u : 1u);
    }
    __syncthreads();
    unsigned int* outp = (unsigned int*)(part16 + (size_t)c * NB16 + base);
    for (int i = t; i < HB_ / 2; i += 256) outp[i] = bins[i];
}

// ---- per-node exclusive prefix across chunks (in u16); totals -> cnt
__global__ void k_colscan(unsigned short* __restrict__ part16,
                          int* __restrict__ cnt) {
    int n = blockIdx.x * 256 + threadIdx.x;      // [0, NB16)
    int run = 0;
    #pragma unroll 8
    for (int c = 0; c < C_; c++) {
        size_t idx = (size_t)c * NB16 + n;
        int v = part16[idx];
        part16[idx] = (unsigned short)run;
        run += v;
    }
    if (n < N_) cnt[n] = run;
}

// ---- exclusive scan over cnt -> ptr
__global__ void k_scan_blk(const int* __restrict__ cnt, int* __restrict__ ptr,
                           int* __restrict__ pblk, int n) {
    __shared__ int sm[256];
    int t = threadIdx.x;
    int i = blockIdx.x * 256 + t;
    int v = (i < n) ? cnt[i] : 0;
    sm[t] = v;
    __syncthreads();
    for (int off = 1; off < 256; off <<= 1) {
        int add = (t >= off) ? sm[t - off] : 0;
        __syncthreads();
        sm[t] += add;
        __syncthreads();
    }
    if (i < n) ptr[i] = sm[t] - v;
    if (t == 255) pblk[blockIdx.x] = sm[t];
}

__global__ void k_scan_part(int* __restrict__ pblk, int nblk) {
    __shared__ int sm[512];
    int t = threadIdx.x;
    int v = (t < nblk) ? pblk[t] : 0;
    sm[t] = v;
    __syncthreads();
    for (int off = 1; off < 512; off <<= 1) {
        int add = (t >= off) ? sm[t - off] : 0;
        __syncthreads();
        sm[t] += add;
        __syncthreads();
    }
    if (t < nblk) pblk[t] = sm[t] - v;
}

__global__ void k_scan_add(int* __restrict__ ptr, const int* __restrict__ pblk, int n) {
    int i = blockIdx.x * 256 + threadIdx.x;
    if (i < n) ptr[i] += pblk[blockIdx.x];
}

// ---- fill: per-(range,chunk); LDS cursors = ptr[n] + chunk prefix
__global__ void k_fill3(const int* __restrict__ row, const int* __restrict__ col,
                        const float* __restrict__ w,
                        const int* __restrict__ ptr,
                        const unsigned short* __restrict__ part16,
                        int2* __restrict__ rec) {
    __shared__ int curs[FB_];
    int r = blockIdx.x >> 6;          // / C_
    int c = blockIdx.x & 63;
    int t = threadIdx.x;
    int base = r * FB_;
    const unsigned short* pp = part16 + (size_t)c * NB16 + base;
    for (int i = t; i < FB_; i += 256) {
        int n = base + i;
        curs[i] = (n < N_) ? (ptr[n] + (int)pp[i]) : 0;
    }
    __syncthreads();
    const int* cp = col + c * CS;
    const int* rp = row + c * CS;
    const float* wp = w + c * CS;
    int e = t;
    for (int it = 0; it < ITER; it++, e += 1024) {
        int v0 = cp[e]       - base;
        int v1 = cp[e + 256] - base;
        int v2 = cp[e + 512] - base;
        int v3 = cp[e + 768] - base;
        if ((unsigned)v0 < (unsigned)FB_) {
            int pos = atomicAdd(&curs[v0], 1);
            rec[pos] = make_int2(rp[e], __float_as_int(wp[e]));
        }
        if ((unsigned)v1 < (unsigned)FB_) {
            int pos = atomicAdd(&curs[v1], 1);
            rec[pos] = make_int2(rp[e + 256], __float_as_int(wp[e + 256]));
        }
        if ((unsigned)v2 < (unsigned)FB_) {
            int pos = atomicAdd(&curs[v2], 1);
            rec[pos] = make_int2(rp[e + 512], __float_as_int(wp[e + 512]));
        }
        if ((unsigned)v3 < (unsigned)FB_) {
            int pos = atomicAdd(&curs[v3], 1);
            rec[pos] = make_int2(rp[e + 768], __float_as_int(wp[e + 768]));
        }
    }
    for (; e < CS; e += 256) {
        int v = cp[e] - base;
        if ((unsigned)v < (unsigned)FB_) {
            int pos = atomicAdd(&curs[v], 1);
            rec[pos] = make_int2(rp[e], __float_as_int(wp[e]));
        }
    }
}

// ---- weighted degree via gather; dinv = rsqrt(deg + 1)
__global__ void k_deg(const int* __restrict__ ptr, const int* __restrict__ cnt,
                      const int2* __restrict__ rec, float* __restrict__ dinv, int n) {
    int i = blockIdx.x * blockDim.x + threadIdx.x;
    if (i >= n) return;
    int st = ptr[i], en = st + cnt[i];
    float d = 0.0f;
    #pragma unroll 4
    for (int e = st; e < en; e++) d += __int_as_float(rec[e].y);
    dinv[i] = rsqrtf(d + 1.0f);
}

// ---- fused: agg 8-wide (+self-loop), h=a@W1+b1, relu, s=h@W2
__global__ void k_aggnode(const int* __restrict__ ptr, const int* __restrict__ cnt,
                          const int2* __restrict__ rec,
                          const float* __restrict__ dinv,
                          const float* __restrict__ x,
                          const float* __restrict__ W1,
                          const float* __restrict__ b1,
                          const float* __restrict__ W2,
                          float* __restrict__ s, int n) {
    __shared__ float sW1[8 * 64];
    __shared__ float sb1[64];
    __shared__ float sW2[64];
    int t = threadIdx.x;
    for (int k = t; k < 8 * 64; k += blockDim.x) sW1[k] = W1[k];
    if (t < 64) { sb1[t] = b1[t]; sW2[t] = W2[t]; }
    __syncthreads();
    int i = blockIdx.x * blockDim.x + t;
    if (i >= n) return;
    float di = dinv[i];
    float sl = di * di;
    const float4* xi = (const float4*)(x + (size_t)i * 8);
    float4 x0 = xi[0], x1 = xi[1];
    float a[8];
    a[0] = sl * x0.x; a[1] = sl * x0.y; a[2] = sl * x0.z; a[3] = sl * x0.w;
    a[4] = sl * x1.x; a[5] = sl * x1.y; a[6] = sl * x1.z; a[7] = sl * x1.w;
    int st = ptr[i], en = st + cnt[i];
    #pragma unroll 2
    for (int e = st; e < en; e++) {
        int2 rc = rec[e];
        int r = rc.x;
        float nrm = dinv[r] * __int_as_float(rc.y) * di;
        const float4* xr = (const float4*)(x + (size_t)r * 8);
        float4 v0 = xr[0], v1 = xr[1];
        a[0] = fmaf(nrm, v0.x, a[0]); a[1] = fmaf(nrm, v0.y, a[1]);
        a[2] = fmaf(nrm, v0.z, a[2]); a[3] = fmaf(nrm, v0.w, a[3]);
        a[4] = fmaf(nrm, v1.x, a[4]); a[5] = fmaf(nrm, v1.y, a[5]);
        a[6] = fmaf(nrm, v1.z, a[6]); a[7] = fmaf(nrm, v1.w, a[7]);
    }
    float acc = 0.0f;
    #pragma unroll
    for (int j = 0; j < 64; j++) {
        float h = sb1[j];
        #pragma unroll
        for (int k = 0; k < 8; k++) h = fmaf(a[k], sW1[k * 64 + j], h);
        acc = fmaf(fmaxf(h, 0.0f), sW2[j], acc);
    }
    s[i] = acc;
}

// ---- layer-2 propagation via gather; norm recomputed (dinv is L2-resident)
__global__ void k_out2(const int* __restrict__ ptr, const int* __restrict__ cnt,
                       const int2* __restrict__ rec,
                       const float* __restrict__ dinv,
                       const float* __restrict__ s,
                       const float* __restrict__ b2,
                       float* __restrict__ out, int n) {
    int i = blockIdx.x * blockDim.x + threadIdx.x;
    if (i >= n) return;
    float di = dinv[i];
    float acc = b2[0] + di * di * s[i];
    int st = ptr[i], en = st + cnt[i];
    #pragma unroll 4
    for (int e = st; e < en; e++) {
        int2 rc = rec[e];
        float nrm = dinv[rc.x] * __int_as_float(rc.y) * di;
        acc = fmaf(nrm, s[rc.x], acc);
    }
    out[i] = acc;
}

extern "C" void kernel_launch(void* const* d_in, const int* in_sizes, int n_in,
                              void* d_out, int out_size, void* d_ws, size_t ws_size,
                              hipStream_t stream) {
    const float* x  = (const float*)d_in[0];
    const int*   ei = (const int*)d_in[1];    // [2, E] int32
    const float* w  = (const float*)d_in[2];
    const float* W1 = (const float*)d_in[3];
    const float* b1 = (const float*)d_in[4];
    const float* W2 = (const float*)d_in[5];
    const float* b2 = (const float*)d_in[6];
    float* out = (float*)d_out;

    const int* row = ei;
    const int* col = ei + E_;

    // ws (ints): cnt[N] | ptr[N] | pblk[512] | dinv[N] | s[N] |
    //            part16 (C_*NB16 u16 = 13.6MB) | rec[E] int2 (25.6MB)  ~41MB
    int*   wsI  = (int*)d_ws;
    int*   cnt  = wsI;
    int*   ptr  = wsI + N_;
    int*   pblk = wsI + 2 * N_;
    float* dinv = (float*)(wsI + 2 * N_ + 512);
    float* s    = dinv + N_;
    unsigned short* part16 = (unsigned short*)(s + N_);
    int2*  rec  = (int2*)(part16 + (size_t)C_ * NB16);

    k_hist3    <<<RH_ * C_, 256, 0, stream>>>(col, part16);
    k_colscan  <<<NB16 / 256, 256, 0, stream>>>(part16, cnt);
    k_scan_blk <<<NBLK, 256, 0, stream>>>(cnt, ptr, pblk, N_);
    k_scan_part<<<1, 512, 0, stream>>>(pblk, NBLK);
    k_scan_add <<<NBLK, 256, 0, stream>>>(ptr, pblk, N_);
    k_fill3    <<<RF_ * C_, 256, 0, stream>>>(row, col, w, ptr, part16, rec);
    k_deg      <<<NBLK, 256, 0, stream>>>(ptr, cnt, rec, dinv, N_);
    k_aggnode  <<<NBLK, 256, 0, stream>>>(ptr, cnt, rec, dinv, x, W1, b1, W2, s, N_);
    k_out2     <<<NBLK, 256, 0, stream>>>(ptr, cnt, rec, dinv, s, b2, out, N_);
}